// Round 2
// baseline (968.441 us; speedup 1.0000x reference)
//
#include <hip/hip_runtime.h>

typedef unsigned int  uint;
typedef unsigned short ushort;
typedef uint  ux4 __attribute__((ext_vector_type(4)));
typedef short sx8 __attribute__((ext_vector_type(8)));
typedef float fx4 __attribute__((ext_vector_type(4)));

__device__ __forceinline__ ushort f2bf(float f){
  union{float f;uint i;}v; v.f=f;
  uint u=v.i;
  return (ushort)((u + 0x7fffu + ((u>>16)&1u)) >> 16);   // RNE f32->bf16
}
__device__ __forceinline__ float bf2f(ushort u){ union{uint i;float f;}v; v.i=((uint)u)<<16; return v.f; }

// TokenDistanceModule (all f32 I/O): per pair (i,j):
//   v = LN_z(z) @ Wz^T + mask*Wa[:,bin(dist(i,j))] ; v = LN_v(2v) ; u = relu(v) @ Wu^T
// Matmuls in bf16 MFMA (inputs rounded), everything else exact f32.
__global__ __launch_bounds__(256, 2)
void tdm_kernel(const float* __restrict__ z, const float* __restrict__ coords,
                const float* __restrict__ tmask,
                const float* __restrict__ Wz, const float* __restrict__ Wa,
                const float* __restrict__ Wu,
                const float* __restrict__ zg, const float* __restrict__ zb,
                const float* __restrict__ vg, const float* __restrict__ vb,
                float* __restrict__ out, int n)
{
  const int tid  = threadIdx.x;
  const int wid  = tid >> 6;
  const int lane = tid & 63;
  const int qd   = lane >> 4;    // quad 0..3
  const int m16  = lane & 15;

  // stride 136 ushorts = 272 B: 16B-aligned rows + bank rotation for b128 frag reads
  __shared__ __align__(16) ushort znS[4][16][136];   // normalized z (bf16)
  __shared__ __align__(16) ushort vS [4][16][72];    // relu(LN(v)) (bf16)
  __shared__ float WaS[64][40];                      // Wa kept f32 (exact a_ij)
  __shared__ int   binS[4][16];
  __shared__ float maskS[4][16];

  // ---- one-time: stage Wa (f32) into LDS ----
  for (int e = tid; e < 64*38; e += 256) WaS[e/38][e%38] = Wa[e];
  __syncthreads();

  // ---- one-time: weight B-fragments (f32 -> bf16) into registers ----
  // B operand layout: lane holds B[k=quad*8+j][ncol=lane&15]; W stored [ncol][k] row-major.
  sx8 wzB[4][4];                  // [nt 0..3][kt 0..3] : Wz 64x128
  #pragma unroll
  for (int nt = 0; nt < 4; ++nt)
    #pragma unroll
    for (int kt = 0; kt < 4; ++kt) {
      union { ushort h[8]; sx8 v; } w;
      const float* p = Wz + (nt*16 + m16)*128 + kt*32 + qd*8;
      #pragma unroll
      for (int j = 0; j < 8; ++j) w.h[j] = f2bf(p[j]);
      wzB[nt][kt] = w.v;
    }
  sx8 wuB[8][2];                  // [nt 0..7][kt 0..1] : Wu 128x64
  #pragma unroll
  for (int nt = 0; nt < 8; ++nt)
    #pragma unroll
    for (int kt = 0; kt < 2; ++kt) {
      union { ushort h[8]; sx8 v; } w;
      const float* p = Wu + (nt*16 + m16)*64 + kt*32 + qd*8;
      #pragma unroll
      for (int j = 0; j < 8; ++j) w.h[j] = f2bf(p[j]);
      wuB[nt][kt] = w.v;
    }

  float vgr[4], vbr[4];
  #pragma unroll
  for (int nt = 0; nt < 4; ++nt) {
    vgr[nt] = vg[nt*16 + m16];
    vbr[nt] = vb[nt*16 + m16];
  }

  const int c0   = (lane & 3) * 32;   // feature quarter this lane stages
  const int row4 = lane >> 2;         // 0..15: staging row (pair within tile)
  const long nn  = (long)n * n;
  const int tiles = (int)(nn >> 4);
  const int waves = gridDim.x * 4;

  for (int tile = blockIdx.x*4 + wid; tile < tiles; tile += waves) {
    const long pBase = (long)tile * 16;
    const uint pB = (uint)pBase;
    const uint i  = pB / (uint)n;
    const uint j0 = pB - i*(uint)n;

    // ---- load z (16 rows x 128 feats f32; lane = quarter of one row) ----
    const float* zp = z + (pBase + row4)*128 + c0;
    fx4 zv[8];
    #pragma unroll
    for (int t = 0; t < 8; ++t) zv[t] = *(const fx4*)(zp + t*4);

    // ---- distance bin for row m16 (exact f32 replication of np math) ----
    {
#pragma clang fp contract(off)
      const float xi0 = coords[i*3+0];
      const float xi1 = coords[i*3+1];
      const float xi2 = coords[i*3+2];
      const uint jj = j0 + (uint)m16;
      const float dx = xi0 - coords[jj*3+0];
      const float dy = xi1 - coords[jj*3+1];
      const float dz = xi2 - coords[jj*3+2];
      const float d2 = (dx*dx + dy*dy) + dz*dz;   // contract(off): left-assoc, no fma
      const float d  = sqrtf(d2);
      int bi = 0;
      #pragma unroll
      for (int k = 0; k < 37; ++k) {
        // np.linspace boundary: f64 3.25 + k*(47.5/36) then cast f32
        const float bk = (float)(3.25 + (double)k * (47.5/36.0));
        bi += (d > bk) ? 1 : 0;
      }
      const float mk = tmask[pBase + m16];
      if (lane < 16) { binS[wid][lane] = bi; maskS[wid][lane] = mk; }
    }

    // ---- layernorm(z) over 128 (4-lane groups own one row) ----
    float s = 0.f, ss = 0.f;
    #pragma unroll
    for (int t = 0; t < 8; ++t)
      #pragma unroll
      for (int w = 0; w < 4; ++w) {
        float a = zv[t][w];
        s += a;
        ss = fmaf(a, a, ss);
      }
    s  += __shfl_xor(s, 1);  s  += __shfl_xor(s, 2);
    ss += __shfl_xor(ss, 1); ss += __shfl_xor(ss, 2);
    const float mean = s * (1.f/128.f);
    const float var  = ss * (1.f/128.f) - mean*mean;
    const float rstd = rsqrtf(var + 1e-5f);
    const float nb   = -mean * rstd;

    // normalize, gamma/beta (f32, L1-hot reload), pack bf16 -> LDS
    #pragma unroll
    for (int t = 0; t < 4; ++t) {
      const fx4 g0 = *(const fx4*)(zg + c0 + t*8);
      const fx4 g1 = *(const fx4*)(zg + c0 + t*8 + 4);
      const fx4 b0 = *(const fx4*)(zb + c0 + t*8);
      const fx4 b1 = *(const fx4*)(zb + c0 + t*8 + 4);
      union { ushort h[8]; ux4 v; } tmp;
      #pragma unroll
      for (int w = 0; w < 4; ++w) {
        float a = fmaf(zv[t*2][w],   rstd, nb);
        float b = fmaf(zv[t*2+1][w], rstd, nb);
        a = fmaf(a, g0[w], b0[w]);
        b = fmaf(b, g1[w], b1[w]);
        tmp.h[w]   = f2bf(a);
        tmp.h[w+4] = f2bf(b);
      }
      *(ux4*)&znS[wid][row4][c0 + t*8] = tmp.v;
    }

    // ---- matmul1: V[16 pairs][64 d] = zn @ Wz^T ----
    fx4 acc[4];
    #pragma unroll
    for (int nt = 0; nt < 4; ++nt) acc[nt] = fx4{0.f,0.f,0.f,0.f};
    #pragma unroll
    for (int kt = 0; kt < 4; ++kt) {
      sx8 aF = *(const sx8*)&znS[wid][m16][kt*32 + qd*8];
      #pragma unroll
      for (int nt = 0; nt < 4; ++nt)
        acc[nt] = __builtin_amdgcn_mfma_f32_16x16x32_bf16(aF, wzB[nt][kt], acc[nt], 0, 0, 0);
    }

    // ---- epilogue 1: + a_ij (exact f32), x2, LN over d=64, gamma/beta, relu -> vS ----
    // C layout: pair row = qd*4+r, col d = nt*16 + m16
    float sv[4] = {0,0,0,0}, ssv[4] = {0,0,0,0};
    #pragma unroll
    for (int r = 0; r < 4; ++r) {
      const int   bi = binS[wid][qd*4 + r];
      const float mk = maskS[wid][qd*4 + r];
      #pragma unroll
      for (int nt = 0; nt < 4; ++nt) {
        float a = WaS[nt*16 + m16][bi];
        float x = 2.f * fmaf(mk, a, acc[nt][r]);
        acc[nt][r] = x;
        sv[r] += x;
        ssv[r] = fmaf(x, x, ssv[r]);
      }
    }
    #pragma unroll
    for (int r = 0; r < 4; ++r) {
      #pragma unroll
      for (int msk = 1; msk < 16; msk <<= 1) {
        sv[r]  += __shfl_xor(sv[r],  msk);
        ssv[r] += __shfl_xor(ssv[r], msk);
      }
      const float mean2 = sv[r] * (1.f/64.f);
      const float var2  = ssv[r] * (1.f/64.f) - mean2*mean2;
      const float rs    = rsqrtf(var2 + 1e-5f);
      const float nb2   = -mean2 * rs;
      #pragma unroll
      for (int nt = 0; nt < 4; ++nt) {
        float y = fmaf(acc[nt][r], rs, nb2);
        y = fmaf(y, vgr[nt], vbr[nt]);
        y = fmaxf(y, 0.f);
        vS[wid][qd*4 + r][nt*16 + m16] = f2bf(y);
      }
    }

    // ---- matmul2: U[16 pairs][128 c] = relu(v) @ Wu^T ----
    fx4 acc2[8];
    #pragma unroll
    for (int nt = 0; nt < 8; ++nt) acc2[nt] = fx4{0.f,0.f,0.f,0.f};
    #pragma unroll
    for (int kt = 0; kt < 2; ++kt) {
      sx8 aF = *(const sx8*)&vS[wid][m16][kt*32 + qd*8];
      #pragma unroll
      for (int nt = 0; nt < 8; ++nt)
        acc2[nt] = __builtin_amdgcn_mfma_f32_16x16x32_bf16(aF, wuB[nt][kt], acc2[nt], 0, 0, 0);
    }

    // ---- store u (f32). Each wave store covers 4 full 64B lines -> write-combines. ----
    #pragma unroll
    for (int r = 0; r < 4; ++r) {
      float* op = out + (pBase + qd*4 + r)*128 + m16;
      #pragma unroll
      for (int nt = 0; nt < 8; ++nt)
        op[nt*16] = acc2[nt][r];
    }
  }
}

extern "C" void kernel_launch(void* const* d_in, const int* in_sizes, int n_in,
                              void* d_out, int out_size, void* d_ws, size_t ws_size,
                              hipStream_t stream)
{
  (void)n_in; (void)out_size; (void)d_ws; (void)ws_size;
  const float* z  = (const float*)d_in[0];
  const float* cc = (const float*)d_in[1];
  const float* tm = (const float*)d_in[2];
  /* d_in[3] = pair_mask: unused by reference */
  const float* Wz = (const float*)d_in[4];
  const float* Wa = (const float*)d_in[5];
  const float* Wu = (const float*)d_in[6];
  const float* zg = (const float*)d_in[7];
  const float* zb = (const float*)d_in[8];
  const float* vg = (const float*)d_in[9];
  const float* vb = (const float*)d_in[10];
  float* out = (float*)d_out;
  const int n = in_sizes[1] / 3;            // center_coords is [1, n, 3]
  dim3 grid(512), block(256);
  tdm_kernel<<<grid, block, 0, stream>>>(z, cc, tm, Wz, Wa, Wu, zg, zb, vg, vb, out, n);
}